// Round 5
// baseline (1078.394 us; speedup 1.0000x reference)
//
#include <hip/hip_runtime.h>

#define L_SEQ 512
#define B_SZ  1024
#define HD    64

__device__ __forceinline__ float fast_sigmoid(float x) {
    return __builtin_amdgcn_rcpf(1.0f + __builtin_amdgcn_exp2f(-1.4426950408889634f * x));
}
__device__ __forceinline__ float fast_tanh(float x) {
    return 1.0f - 2.0f * __builtin_amdgcn_rcpf(1.0f + __builtin_amdgcn_exp2f(2.8853900817779268f * x));
}

// Keep a value live in a register with an opaque (non-remat, non-sinkable) def.
#define PIN(x) asm volatile("" : "+v"(x))

// 64-element dot product: sm is a wave-uniform LDS base (broadcast float4 reads),
// w is a per-thread register array. Two accumulators hide FMA dep latency.
__device__ __forceinline__ float dot64(const float* sm, const float* w) {
    const float4* p = (const float4*)sm;
    float s0 = 0.0f, s1 = 0.0f;
#pragma unroll
    for (int q = 0; q < 16; q += 2) {
        float4 u = p[q];
        float4 v = p[q + 1];
        s0 = fmaf(u.x, w[4 * q + 0], s0); s0 = fmaf(u.y, w[4 * q + 1], s0);
        s0 = fmaf(u.z, w[4 * q + 2], s0); s0 = fmaf(u.w, w[4 * q + 3], s0);
        s1 = fmaf(v.x, w[4 * q + 4], s1); s1 = fmaf(v.y, w[4 * q + 5], s1);
        s1 = fmaf(v.z, w[4 * q + 6], s1); s1 = fmaf(v.w, w[4 * q + 7], s1);
    }
    return s0 + s1;
}

// 1024 blocks x 192 threads. Block = one batch row, runs all 512 steps.
// Wave 0 = z gate, wave 1 = r gate, wave 2 = candidate; lane j = output column.
// Each thread holds one full 128-row weight column in VGPRs (wA = part dotted
// with xt, wB = part dotted with h or r*h). No partial-sum reductions; 2
// barriers/step. Wave 0 prefetches the next step's embedding row (2-deep pipe).
__global__ void __launch_bounds__(192)
__attribute__((amdgpu_waves_per_eu(2, 3)))
gru_fused_kernel(
    const int* __restrict__ xind, const float* __restrict__ emb,
    const float* __restrict__ Wz, const float* __restrict__ Wr,
    const float* __restrict__ Wh, float* __restrict__ out)
{
    __shared__ float sm_x[64];    // xt
    __shared__ float sm_h[64];    // h
    __shared__ float sm_rh[64];   // r * h
    __shared__ float sm_z[64];    // z gate

    const int j  = threadIdx.x & 63;
    const int wv = threadIdx.x >> 6;   // wave-uniform
    const int b  = blockIdx.x;

    // Wz/Wr: rows 0..63 multiply xt, rows 64..127 multiply h.
    // Wh:    rows 0..63 multiply r*h, rows 64..127 multiply xt.
    const float* W = (wv == 0) ? Wz : (wv == 1) ? Wr : Wh;
    const int offA = (wv == 2) ? 64 * 64 : 0;   // rows dotted with xt
    const int offB = 64 * 64 - offA;            // rows dotted with h / r*h

    float wA[64], wB[64];
#pragma unroll
    for (int k = 0; k < 64; ++k) {
        wA[k] = W[offA + k * 64 + j];
        wB[k] = W[offB + k * 64 + j];
    }
#pragma unroll
    for (int k = 0; k < 64; ++k) { PIN(wA[k]); PIN(wB[k]); }

    // ---- init: xt(0), h=0, idx for t=1 ----
    int idxn = 0;
    if (wv == 0) {
        sm_x[j] = emb[(size_t)xind[b] * HD + j];
        idxn = xind[B_SZ + b];
        sm_z[j] = 0.0f;
    } else if (wv == 1) {
        sm_h[j] = 0.0f;
        sm_rh[j] = 0.0f;
    }
    __syncthreads();

    float* outp = out + (size_t)b * HD + j;
    for (int t = 0; t < L_SEQ; ++t) {
        // ---- prefetch (wave 0): emb row for t+1, index for t+2 ----
        float ev = 0.0f;
        int idx2 = idxn;
        if (wv == 0) {
            if (t < L_SEQ - 1) ev = emb[(size_t)idxn * HD + j];
            if (t < L_SEQ - 2) idx2 = xind[(t + 2) * B_SZ + b];
        }

        // ---- Phase A ----
        float a0 = dot64(sm_x, wA);            // all waves: x-part dot
        if (wv < 2) {
            float a1 = dot64(sm_h, wB);        // h-part dot
            float g = fast_sigmoid(a0 + a1);
            if (wv == 0) sm_z[j] = g;          // z
            else         sm_rh[j] = g * sm_h[j]; // r * h
        }
        __syncthreads();

        // ---- Phase B ----
        if (wv == 2) {
            float a2 = dot64(sm_rh, wB);       // (r*h)-part dot
            float hc = fast_tanh(a0 + a2);
            float ho = sm_h[j];
            float z  = sm_z[j];
            float hn = fmaf(z, hc - ho, ho);
            sm_h[j] = hn;
            outp[0] = hn;
            if (t == L_SEQ - 1)
                out[(size_t)L_SEQ * B_SZ * HD + (size_t)b * HD + j] = hn;
        } else if (wv == 0) {
            if (t < L_SEQ - 1) sm_x[j] = ev;   // commit xt for t+1
            idxn = idx2;
        }
        outp += (size_t)B_SZ * HD;
        __syncthreads();
    }
}

extern "C" void kernel_launch(void* const* d_in, const int* in_sizes, int n_in,
                              void* d_out, int out_size, void* d_ws, size_t ws_size,
                              hipStream_t stream) {
    (void)in_sizes; (void)n_in; (void)out_size; (void)d_ws; (void)ws_size;
    const int*   x   = (const int*)  d_in[0];
    const float* emb = (const float*)d_in[1];
    const float* Wz  = (const float*)d_in[2];
    const float* Wr  = (const float*)d_in[3];
    const float* Wh  = (const float*)d_in[4];
    float* out = (float*)d_out;

    gru_fused_kernel<<<dim3(B_SZ), dim3(192), 0, stream>>>(x, emb, Wz, Wr, Wh, out);
}